// Round 9
// baseline (157.701 us; speedup 1.0000x reference)
//
#include <hip/hip_runtime.h>
#include <hip/hip_bf16.h>
#include <stdint.h>

#define G_ 24
#define B_ 256
#define I_ 512
#define E_ 512
#define K_ (G_ * I_)   // 12288
// Persistent 3-item schedule: grid 512 = 2/CU exact. WG owns (m-half, n-quarter, s of 8);
// processes h in {h0, h0+8, h0+16} as one flat 72-ktile (BK=64) loop.

typedef __hip_bfloat16 bf16;
typedef __bf16 bf16x8 __attribute__((ext_vector_type(8)));
typedef float f32x4 __attribute__((ext_vector_type(4)));

// ---------- input f32 -> bf16 ----------
__global__ void cvt_in_kernel(const float* __restrict__ in, bf16* __restrict__ out, int n4) {
  int idx = blockIdx.x * blockDim.x + threadIdx.x;
  if (idx >= n4) return;
  float4 v = reinterpret_cast<const float4*>(in)[idx];
  union { bf16 h[4]; uint2 u; } pk;
  pk.h[0] = __float2bfloat16(v.x);
  pk.h[1] = __float2bfloat16(v.y);
  pk.h[2] = __float2bfloat16(v.z);
  pk.h[3] = __float2bfloat16(v.w);
  reinterpret_cast<uint2*>(out)[idx] = pk.u;
}

// ---------- W[g][i][e] f32 -> Wt[g][e][i] bf16 ----------
__global__ void transpose_w_kernel(const float* __restrict__ W, bf16* __restrict__ Wt) {
  __shared__ float tile[32][33];
  const int g = blockIdx.z;
  const int i0 = blockIdx.x * 32;
  const int e0 = blockIdx.y * 32;
  const float* src = W + (size_t)g * (I_ * E_) + (size_t)(i0 + threadIdx.y) * E_ + e0 + threadIdx.x;
  #pragma unroll
  for (int r = 0; r < 32; r += 8)
    tile[threadIdx.y + r][threadIdx.x] = src[(size_t)r * E_];
  __syncthreads();
  bf16* dst = Wt + (size_t)g * (I_ * E_) + (size_t)(e0 + threadIdx.y) * I_ + i0 + threadIdx.x;
  #pragma unroll
  for (int r = 0; r < 32; r += 8)
    dst[(size_t)r * I_] = __float2bfloat16(tile[threadIdx.x][threadIdx.y + r]);
}

// ---------- out[b][h][e] = bias[e] ----------
__global__ void init_out_kernel(const float* __restrict__ bias, float* __restrict__ out, int n4) {
  int idx = blockIdx.x * blockDim.x + threadIdx.x;
  if (idx >= n4) return;
  int e4 = idx & 127;  // (E/4)=128 float4 per (b,h) row
  reinterpret_cast<float4*>(out)[idx] = reinterpret_cast<const float4*>(bias)[e4];
}

// ================= GEMM: BM=BN=128, BK=64, 4 waves of 64x64, persistent 3-item =================
// out[b,h,e] += sum_k A[b,k] * Wt[(k/512 - h)%24][e][k%512]
// Grid 512 = 2 WG/CU exact (LDS 64 KB dbuf), zero raggedness.
// XCD <-> (m,n) bijection: xcd = bid&7 -> m0 = (xcd&1)*128, n0 = (xcd>>1)*128.
//   Per-XCD W-slice = 24g x 128e x 512i x 2B = 3.1 MB, L2-resident all kernel.
// inner = bid>>3 (0..63): s = inner&7 (k-octant, 1536 k each), h0 = inner>>3 (0..7).
// Items j=0..2: h = h0 + 8j; flat 72-ktile loop, buffer parity continuous across
// items; next item's first tile staged BEFORE the epilogue (atomics hide in flight).
// 2-barrier counted-vmcnt loop (vmcnt(8) steady), XOR slot-swizzle both sides.
#define FENCE() asm volatile("" ::: "memory")
#define BAR()   __builtin_amdgcn_s_barrier()
#define VMW(N)  asm volatile("s_waitcnt vmcnt(" #N ")" ::: "memory")

__device__ __forceinline__ void gload16(const bf16* g, bf16* l) {
  __builtin_amdgcn_global_load_lds((const __attribute__((address_space(1))) void*)g,
                                   (__attribute__((address_space(3))) void*)l, 16, 0, 0);
}

__global__ __launch_bounds__(256, 2) void gemm_kernel(
    const bf16* __restrict__ A,   // [256][12288]
    const bf16* __restrict__ Wt,  // [24][512(e)][512(i)]
    float* __restrict__ out) {    // [256][24][512], pre-init'd with bias

  __shared__ __align__(16) bf16 ldsA[2][128 * 64];  // 32 KB
  __shared__ __align__(16) bf16 ldsB[2][128 * 64];  // 32 KB

  const int tid  = threadIdx.x;
  const int lane = tid & 63;
  const int wave = tid >> 6;     // 0..3
  const int wr   = wave >> 1;    // 0..1 -> 64 M-rows
  const int wc   = wave & 1;     // 0..1 -> 64 N-cols
  const int rsel = lane & 15;
  const int q    = lane >> 4;    // 0..3

  const int bid   = blockIdx.x;        // 0..511
  const int xcd   = bid & 7;
  const int m0    = (xcd & 1) * 128;
  const int n0    = (xcd >> 1) * 128;  // 0..3 -> n quarter
  const int inner = bid >> 3;          // 0..63
  const int s     = inner & 7;         // k-octant
  const int h0    = inner >> 3;        // 0..7

  // ---- loop-invariant staging offsets (4 chunks per thread per operand) ----
  // chunk c (0..1023): row = c>>3, linear slot = c&7, source slot = (c&7)^(row&7)
  size_t aoff[4], boff[4];
  int ldso[4];
  #pragma unroll
  for (int j = 0; j < 4; ++j) {
    int c    = tid + j * 256;
    int row  = c >> 3;
    int slot = (c & 7) ^ (row & 7);
    aoff[j] = (size_t)row * K_ + slot * 8;
    boff[j] = (size_t)row * I_ + slot * 8;
    ldso[j] = c * 8;
  }

  // ---- loop-invariant ds_read byte offsets (kk=0; kk=1 is ^64) ----
  int aro[4], bro[4];
  #pragma unroll
  for (int mi = 0; mi < 4; ++mi) {
    int r = wr * 64 + mi * 16 + rsel;
    aro[mi] = r * 128 + ((q ^ (r & 7)) << 4);
  }
  #pragma unroll
  for (int ni = 0; ni < 4; ++ni) {
    int r = wc * 64 + ni * 16 + rsel;
    bro[ni] = r * 128 + ((q ^ (r & 7)) << 4);
  }

  f32x4 acc[4][4];
  #pragma unroll
  for (int i = 0; i < 4; ++i)
    #pragma unroll
    for (int j = 0; j < 4; ++j)
      acc[i][j] = (f32x4){0.f, 0.f, 0.f, 0.f};

  // stage flat-ktile kt (0..71) into buffer kt&1
  auto stage = [&](int kt) {
    const int item = kt / 24;          // 0..2 (const-div -> magic mul)
    const int lt   = kt - item * 24;
    const int t    = s * 24 + lt;      // global k-tile 0..191
    const int h    = h0 + item * 8;
    const int g    = t >> 3;
    int gsrc = g - h; if (gsrc < 0) gsrc += G_;
    const int i0 = (t & 7) * 64;
    const bf16* Ab = A + (size_t)m0 * K_ + (size_t)t * 64;
    const bf16* Bb = Wt + (size_t)gsrc * (I_ * E_) + (size_t)n0 * I_ + i0;
    const int b = kt & 1;
    #pragma unroll
    for (int j = 0; j < 4; ++j)
      gload16(Ab + aoff[j], &ldsA[b][ldso[j]]);
    #pragma unroll
    for (int j = 0; j < 4; ++j)
      gload16(Bb + boff[j], &ldsB[b][ldso[j]]);
  };

  stage(0);

  for (int kt = 0; kt < 72; ++kt) {
    if (kt + 1 < 72) {
      stage(kt + 1);
      VMW(8);  // retire tile kt's 8 loads; keep tile kt+1's 8 in flight
    } else {
      VMW(0);
    }
    FENCE(); BAR(); FENCE();

    const int cur = kt & 1;
    const char* Al = (const char*)&ldsA[cur][0];
    const char* Bl = (const char*)&ldsB[cur][0];
    #pragma unroll
    for (int kk = 0; kk < 2; ++kk) {
      const int x = kk << 6;
      bf16x8 af[4], bfr[4];
      #pragma unroll
      for (int mi = 0; mi < 4; ++mi)
        af[mi] = *(const bf16x8*)(Al + (aro[mi] ^ x));
      #pragma unroll
      for (int ni = 0; ni < 4; ++ni)
        bfr[ni] = *(const bf16x8*)(Bl + (bro[ni] ^ x));
      #pragma unroll
      for (int mi = 0; mi < 4; ++mi)
        #pragma unroll
        for (int ni = 0; ni < 4; ++ni)
          acc[mi][ni] = __builtin_amdgcn_mfma_f32_16x16x32_bf16(
              af[mi], bfr[ni], acc[mi][ni], 0, 0, 0);
    }

    asm volatile("s_waitcnt lgkmcnt(0)" ::: "memory");
    BAR(); FENCE();

    // ---- item boundary: epilogue for h = h0 + 8*item (next item's loads in flight)
    if ((kt % 24) == 23) {
      const int h = h0 + (kt / 24) * 8;
      #pragma unroll
      for (int mi = 0; mi < 4; ++mi) {
        #pragma unroll
        for (int ni = 0; ni < 4; ++ni) {
          int ecol  = n0 + wc * 64 + ni * 16 + rsel;
          int brow0 = m0 + wr * 64 + mi * 16 + q * 4;
          float* o = out + (size_t)brow0 * (G_ * E_) + (size_t)h * E_ + ecol;
          #pragma unroll
          for (int r = 0; r < 4; ++r)
            atomicAdd(o + (size_t)r * (G_ * E_), acc[mi][ni][r]);
          acc[mi][ni] = (f32x4){0.f, 0.f, 0.f, 0.f};
        }
      }
    }
  }
}

extern "C" void kernel_launch(void* const* d_in, const int* in_sizes, int n_in,
                              void* d_out, int out_size, void* d_ws, size_t ws_size,
                              hipStream_t stream) {
  const float* in   = (const float*)d_in[0];
  const float* w    = (const float*)d_in[1];
  const float* bias = (const float*)d_in[2];
  float* out = (float*)d_out;

  bf16* A_bf = (bf16*)d_ws;                                   // 6.29 MB
  bf16* Wt   = (bf16*)((char*)d_ws + (size_t)B_ * K_ * 2);    // 12.58 MB

  const int n4in  = (B_ * K_) / 4;        // 786432
  const int n4out = (B_ * G_ * E_) / 4;   // 786432
  cvt_in_kernel<<<n4in / 256, 256, 0, stream>>>(in, A_bf, n4in);
  transpose_w_kernel<<<dim3(E_ / 32, I_ / 32, G_), dim3(32, 8), 0, stream>>>(w, Wt);
  init_out_kernel<<<n4out / 256, 256, 0, stream>>>(bias, out, n4out);
  gemm_kernel<<<512, 256, 0, stream>>>(A_bf, Wt, out);
}

// Round 10
// 137.797 us; speedup vs baseline: 1.1444x; 1.1444x over previous
//
#include <hip/hip_runtime.h>
#include <hip/hip_bf16.h>
#include <stdint.h>

#define G_ 24
#define B_ 256
#define I_ 512
#define E_ 512
#define K_ (G_ * I_)   // 12288
// splitK=5 (uneven 77/77/77/77/76 BK=32 steps), grid 960 = 8 xcd-combos x 120 (s,h).
// 4 WG/CU capacity (LDS 32KB, VGPR<=128): 960/1024 slots, single dispatch round.

typedef __hip_bfloat16 bf16;
typedef __bf16 bf16x8 __attribute__((ext_vector_type(8)));
typedef float f32x4 __attribute__((ext_vector_type(4)));

// ---------- fused: input f32 -> bf16  AND  out[b][h][e] = bias[e] ----------
__global__ void prep_kernel(const float* __restrict__ in, bf16* __restrict__ outA,
                            const float* __restrict__ bias, float* __restrict__ outO, int n4) {
  int idx = blockIdx.x * blockDim.x + threadIdx.x;
  if (idx >= n4) return;
  float4 v = reinterpret_cast<const float4*>(in)[idx];
  union { bf16 h[4]; uint2 u; } pk;
  pk.h[0] = __float2bfloat16(v.x);
  pk.h[1] = __float2bfloat16(v.y);
  pk.h[2] = __float2bfloat16(v.z);
  pk.h[3] = __float2bfloat16(v.w);
  reinterpret_cast<uint2*>(outA)[idx] = pk.u;
  int e4 = idx & 127;  // (E/4)=128 float4 per (b,h) row
  reinterpret_cast<float4*>(outO)[idx] = reinterpret_cast<const float4*>(bias)[e4];
}

// ---------- W[g][i][e] f32 -> Wt[g][e][i] bf16 ----------
__global__ void transpose_w_kernel(const float* __restrict__ W, bf16* __restrict__ Wt) {
  __shared__ float tile[32][33];
  const int g = blockIdx.z;
  const int i0 = blockIdx.x * 32;
  const int e0 = blockIdx.y * 32;
  const float* src = W + (size_t)g * (I_ * E_) + (size_t)(i0 + threadIdx.y) * E_ + e0 + threadIdx.x;
  #pragma unroll
  for (int r = 0; r < 32; r += 8)
    tile[threadIdx.y + r][threadIdx.x] = src[(size_t)r * E_];
  __syncthreads();
  bf16* dst = Wt + (size_t)g * (I_ * E_) + (size_t)(e0 + threadIdx.y) * I_ + i0 + threadIdx.x;
  #pragma unroll
  for (int r = 0; r < 32; r += 8)
    dst[(size_t)r * I_] = __float2bfloat16(tile[threadIdx.x][threadIdx.y + r]);
}

// ================= GEMM: BM=128, BN=128, BK=32, 4 waves of 64x64, splitK=5 =================
// out[b,h,e] += sum_k A[b,k] * Wt[(k/512 - h)%24][e][k%512]
// R7 base (proven: FETCH 75MB, VALU 10%, conflicts 0) with ONE variable changed:
// occupancy 3 -> 4 WG/CU (16 waves/CU), via launch_bounds(256,4) + grid 960.
// XCD-pinned decode unchanged: xcd = bid&7 fixes (m0, n0) -> per-XCD W-slice
// 24g x 128e x 512i x 2B = 3.1 MB L2-resident; inner spans (s of 5, h of 24).
// All ds_read offsets and staging source offsets loop-invariant (BK=32).
// Swizzle both-sides: source slot = (c&3)^((c>>3)&3); read slot = q^((r>>1)&3).
#define FENCE() asm volatile("" ::: "memory")
#define BAR()   __builtin_amdgcn_s_barrier()
#define VMW(N)  asm volatile("s_waitcnt vmcnt(" #N ")" ::: "memory")

__device__ __forceinline__ void gload16(const bf16* g, bf16* l) {
  __builtin_amdgcn_global_load_lds((const __attribute__((address_space(1))) void*)g,
                                   (__attribute__((address_space(3))) void*)l, 16, 0, 0);
}

__global__ __launch_bounds__(256, 4) void gemm_kernel(
    const bf16* __restrict__ A,   // [256][12288]
    const bf16* __restrict__ Wt,  // [24][512(e)][512(i)]
    float* __restrict__ out) {    // [256][24][512], pre-init'd with bias

  __shared__ __align__(16) bf16 ldsA[2][128 * 32];  // 16 KB
  __shared__ __align__(16) bf16 ldsB[2][128 * 32];  // 16 KB

  const int tid  = threadIdx.x;
  const int lane = tid & 63;
  const int wave = tid >> 6;     // 0..3
  const int wr   = wave >> 1;    // 0..1 -> 64 M-rows
  const int wc   = wave & 1;     // 0..1 -> 64 N-cols
  const int rsel = lane & 15;
  const int q    = lane >> 4;    // k-slot 0..3 (8 bf16 each)

  // XCD-pinned decode: xcd = bid&7 fixes (m0, n0); inner spans (s, h).
  const int bid   = blockIdx.x;        // 0..959
  const int m0    = (bid & 1) * 128;
  const int n0    = ((bid >> 1) & 3) * 128;
  const int inner = bid >> 3;          // 0..119
  const int s     = inner % 5;         // split 0..4
  const int h     = inner / 5;         // 0..23

  // uneven split: 77 steps for s<4, 76 for s=4
  const int T0 = s * 77;
  const int NS = (s < 4) ? 77 : 76;

  // ---- loop-invariant staging offsets (2 chunks per thread per tile) ----
  // chunk c: row = c>>2, linear slot = c&3, source slot = (c&3) ^ ((c>>3)&3)
  const int c0 = tid, c1 = tid + 256;
  const size_t aoff0 = (size_t)(c0 >> 2) * K_ + (((c0 & 3) ^ ((c0 >> 3) & 3)) << 3);
  const size_t aoff1 = (size_t)(c1 >> 2) * K_ + (((c1 & 3) ^ ((c1 >> 3) & 3)) << 3);
  const size_t boff0 = (size_t)(c0 >> 2) * I_ + (((c0 & 3) ^ ((c0 >> 3) & 3)) << 3);
  const size_t boff1 = (size_t)(c1 >> 2) * I_ + (((c1 & 3) ^ ((c1 >> 3) & 3)) << 3);

  // ---- loop-invariant ds_read byte offsets (within one 8 KB buffer) ----
  int aro[4], bro[4];
  #pragma unroll
  for (int mi = 0; mi < 4; ++mi) {
    int r = wr * 64 + mi * 16 + rsel;
    aro[mi] = r * 64 + ((q ^ ((r >> 1) & 3)) << 4);
  }
  #pragma unroll
  for (int ni = 0; ni < 4; ++ni) {
    int r = wc * 64 + ni * 16 + rsel;
    bro[ni] = r * 64 + ((q ^ ((r >> 1) & 3)) << 4);
  }

  f32x4 acc[4][4];
  #pragma unroll
  for (int i = 0; i < 4; ++i)
    #pragma unroll
    for (int j = 0; j < 4; ++j)
      acc[i][j] = (f32x4){0.f, 0.f, 0.f, 0.f};

  // stage global k-step t (0..383) into buffer b
  auto stage = [&](int t, int b) {
    const int g     = t >> 4;          // 16 BK=32 steps per g
    const int gamma = t & 15;
    int gsrc = g - h; if (gsrc < 0) gsrc += G_;
    const bf16* Ab = A + (size_t)m0 * K_ + (size_t)t * 32;
    const bf16* Bb = Wt + (size_t)gsrc * (I_ * E_) + (size_t)n0 * I_ + gamma * 32;
    gload16(Ab + aoff0, &ldsA[b][(size_t)c0 * 8]);
    gload16(Ab + aoff1, &ldsA[b][(size_t)c1 * 8]);
    gload16(Bb + boff0, &ldsB[b][(size_t)c0 * 8]);
    gload16(Bb + boff1, &ldsB[b][(size_t)c1 * 8]);
  };

  stage(T0, 0);

  for (int lt = 0; lt < NS; ++lt) {
    const int cur = lt & 1;
    if (lt + 1 < NS) {
      stage(T0 + lt + 1, cur ^ 1);
      VMW(4);  // retire step t's 4 loads; keep step t+1's 4 in flight
    } else {
      VMW(0);
    }
    FENCE(); BAR(); FENCE();

    bf16x8 af[4], bfr[4];
    #pragma unroll
    for (int mi = 0; mi < 4; ++mi)
      af[mi] = *(const bf16x8*)((const char*)(&ldsA[cur][0]) + aro[mi]);
    #pragma unroll
    for (int ni = 0; ni < 4; ++ni)
      bfr[ni] = *(const bf16x8*)((const char*)(&ldsB[cur][0]) + bro[ni]);
    #pragma unroll
    for (int mi = 0; mi < 4; ++mi)
      #pragma unroll
      for (int ni = 0; ni < 4; ++ni)
        acc[mi][ni] = __builtin_amdgcn_mfma_f32_16x16x32_bf16(
            af[mi], bfr[ni], acc[mi][ni], 0, 0, 0);

    asm volatile("s_waitcnt lgkmcnt(0)" ::: "memory");
    BAR(); FENCE();
  }

  // ---- epilogue: atomic split-K combine. C/D: col=lane&15, row=(lane>>4)*4+reg
  #pragma unroll
  for (int mi = 0; mi < 4; ++mi) {
    #pragma unroll
    for (int ni = 0; ni < 4; ++ni) {
      int ecol  = n0 + wc * 64 + ni * 16 + rsel;
      int brow0 = m0 + wr * 64 + mi * 16 + q * 4;
      float* o = out + (size_t)brow0 * (G_ * E_) + (size_t)h * E_ + ecol;
      #pragma unroll
      for (int r = 0; r < 4; ++r)
        atomicAdd(o + (size_t)r * (G_ * E_), acc[mi][ni][r]);
    }
  }
}

extern "C" void kernel_launch(void* const* d_in, const int* in_sizes, int n_in,
                              void* d_out, int out_size, void* d_ws, size_t ws_size,
                              hipStream_t stream) {
  const float* in   = (const float*)d_in[0];
  const float* w    = (const float*)d_in[1];
  const float* bias = (const float*)d_in[2];
  float* out = (float*)d_out;

  bf16* A_bf = (bf16*)d_ws;                                   // 6.29 MB
  bf16* Wt   = (bf16*)((char*)d_ws + (size_t)B_ * K_ * 2);    // 12.58 MB

  const int n4 = (B_ * K_) / 4;  // 786432 (same for A-cvt and out-init domains)
  prep_kernel<<<n4 / 256, 256, 0, stream>>>(in, A_bf, bias, out, n4);
  transpose_w_kernel<<<dim3(E_ / 32, I_ / 32, G_), dim3(32, 8), 0, stream>>>(w, Wt);
  gemm_kernel<<<960, 256, 0, stream>>>(A_bf, Wt, out);
}